// Round 1
// baseline (471.742 us; speedup 1.0000x reference)
//
#include <hip/hip_runtime.h>

typedef unsigned int uint_t;
typedef unsigned short ushort_t;

using f32x4 = __attribute__((ext_vector_type(4))) float;
using bf16x8 = __attribute__((ext_vector_type(8))) short;

#define D_MODEL 2048
#define N_HEADS 16
#define N_KV    4
#define HD      128
#define KV_DIM  (N_KV * HD)          // 512
#define NQKV    (D_MODEL + 2*KV_DIM) // 3072
#define SEQ     2048
#define NB      4
#define MROWS   (NB * SEQ)           // 8192
#define NKT     32                   // K/64, K=2048 for both GEMMs
#define SM_SCALE 0.08838834764831845f  // 1/sqrt(128)

__device__ __forceinline__ ushort_t f2bf(float f) {
    uint_t u = __float_as_uint(f);
    u = (u + 0x7FFFu + ((u >> 16) & 1u)) >> 16;   // RNE
    return (ushort_t)u;
}

// async global->LDS, 16 B/lane, lands at (wave-uniform lds base) + lane*16
__device__ __forceinline__ void gload16(const ushort_t* g, ushort_t* l) {
    __builtin_amdgcn_global_load_lds(
        (const __attribute__((address_space(1))) unsigned int*)g,
        (__attribute__((address_space(3))) unsigned int*)l, 16, 0, 0);
}

#define VMCNT(N) asm volatile("s_waitcnt vmcnt(" #N ")" ::: "memory")

// ---------------------------------------------------------------- conv_x
__global__ __launch_bounds__(256) void conv_x_kernel(const float* __restrict__ in,
                                                     ushort_t* __restrict__ out, int n) {
    int i = (blockIdx.x * 256 + threadIdx.x) * 4;
    if (i >= n) return;
    float4 v = *(const float4*)&in[i];
    ushort_t o[4] = {f2bf(v.x), f2bf(v.y), f2bf(v.z), f2bf(v.w)};
    *(uint2*)&out[i] = *(uint2*)o;
}

// ------------------------------------------------------ transpose + cast
// W [K][Nout] fp32 -> WT [Nout][K] bf16
__global__ __launch_bounds__(256) void conv_wt_kernel(const float* __restrict__ W,
                                                      ushort_t* __restrict__ WT,
                                                      int K, int Nout) {
    __shared__ float tile[32][33];
    int n0 = blockIdx.x * 32, k0 = blockIdx.y * 32;
    int tx = threadIdx.x, ty = threadIdx.y;  // (32, 8)
    for (int i = 0; i < 4; ++i)
        tile[ty + 8*i][tx] = W[(size_t)(k0 + ty + 8*i) * Nout + n0 + tx];
    __syncthreads();
    for (int i = 0; i < 4; ++i)
        WT[(size_t)(n0 + ty + 8*i) * K + k0 + tx] = f2bf(tile[tx][ty + 8*i]);
}

// ======================================================================
// 256x256 8-phase GEMM core (T2+T3+T4+T5). 512 thr = 8 waves (2M x 4N),
// wave tile 128x64. BK=64 as two K-halves of 32. LDS = 2buf x 2kh x
// (256rows x 32k) x {A,B} = 128 KiB. Per K-tile: 4 phases, each
// {ds_read subtile; stage 1 half (2 gload16); barrier; setprio(1);
//  16 MFMA; setprio(0); [vmcnt]; barrier}. vmcnt(8) at odd phases only
// (never 0 mid-loop): every drained half was issued 4-5 phases earlier.
// Slot safety: kh0 slot of buf is free after phase1 (staged at phase2
// for K-tile j+2); kh1 slot of buf^1 free after prev tile's phase3
// (staged at phase0 for j+1). LDS layout packs 2 M-rows per 128-B LDS
// row; chunk = ((row&1)<<2 | kchunk) ^ (lrow&7): each aligned 8-lane
// group of ds_read_b128 hits 8 distinct 16B chunks -> conflict-free.
// ======================================================================
#define G256_PRELUDE                                                               \
    const int t = threadIdx.x;                                                     \
    const int wid = t >> 6, lane = t & 63, quad = lane >> 4, r = lane & 15;        \
    const int wr = wid >> 2, wc = wid & 3;                                         \
    int srow[2], skc[2], sdst[2];                                                  \
    for (int l = 0; l < 2; ++l) {                                                  \
        int u = l * 512 + t, lrow = u >> 3, cc = (u & 7) ^ (lrow & 7);             \
        srow[l] = lrow * 2 + (cc >> 2); skc[l] = (cc & 3) * 8; sdst[l] = u * 8;    \
    }                                                                              \
    const int swz  = ((((r & 1) << 2) | quad) ^ ((r >> 1) & 7)) * 8;               \
    const int aoff = (wr * 64 + (r >> 1)) * 64 + swz;                              \
    const int boff = (wc * 32 + (r >> 1)) * 64 + swz;                              \
    f32x4 acc[8][4] = {};                                                          \
    bf16x8 bfr[4];

// stage one K-half (256 rows x 32 k) of an operand; global source is
// pre-inverse-swizzled so LDS stays linear for the DMA (rule 21).
#define STAGE1(PTR, ROWBASE, kt, kh, DST, dbuf)                                    \
    if ((kt) < NKT) {                                                              \
        for (int l = 0; l < 2; ++l)                                                \
            gload16(&PTR[(size_t)((ROWBASE) + srow[l]) * 2048 +                    \
                         (kt) * 64 + (kh) * 32 + skc[l]],                          \
                    &DST[dbuf][kh][0] + sdst[l]);                                  \
    }

#define PHASE(buf, kh, mh, STAGE_STMT, VM_STMT)                                    \
    {                                                                              \
        bf16x8 af[4];                                                              \
        for (int i = 0; i < 4; ++i)                                                \
            af[i] = *(const bf16x8*)&As[buf][kh][aoff + ((mh) * 4 + i) * 512];     \
        if ((mh) == 0)                                                             \
            for (int jf = 0; jf < 4; ++jf)                                         \
                bfr[jf] = *(const bf16x8*)&Bs[buf][kh][boff + jf * 512];           \
        STAGE_STMT;                                                                \
        __builtin_amdgcn_s_barrier();                                              \
        __builtin_amdgcn_s_setprio(1);                                             \
        for (int i = 0; i < 4; ++i)                                                \
            for (int jf = 0; jf < 4; ++jf)                                         \
                acc[(mh) * 4 + i][jf] = __builtin_amdgcn_mfma_f32_16x16x32_bf16(   \
                    af[i], bfr[jf], acc[(mh) * 4 + i][jf], 0, 0, 0);               \
        __builtin_amdgcn_s_setprio(0);                                             \
        VM_STMT;                                                                   \
        __builtin_amdgcn_s_barrier();                                              \
    }

#define KTILE(j, buf)                                                              \
    PHASE(buf, 0, 0, STAGE1(Aptr, bm, (j) + 1, 1, As, (buf) ^ 1), ;)               \
    PHASE(buf, 0, 1, STAGE1(Bptr, bn, (j) + 1, 1, Bs, (buf) ^ 1),                  \
          { if ((j) + 1 < NKT) { VMCNT(8); } else { VMCNT(0); } })                 \
    PHASE(buf, 1, 0, STAGE1(Aptr, bm, (j) + 2, 0, As, buf), ;)                     \
    PHASE(buf, 1, 1, STAGE1(Bptr, bn, (j) + 2, 0, Bs, buf),                        \
          { if ((j) + 2 < NKT) { VMCNT(8); }                                       \
            else if ((j) + 1 < NKT) { VMCNT(4); }                                  \
            else { VMCNT(0); } })

// prologue: A0(0) B0(0) A1(0) B1(0) A0(1) B0(1); vmcnt(8) drains K-tile0's
// kh0 halves (oldest 4 loads); kh1 halves drain at phase1's vmcnt(8).
#define G256_MAIN_LOOP                                                             \
    STAGE1(Aptr, bm, 0, 0, As, 0);                                                 \
    STAGE1(Bptr, bn, 0, 0, Bs, 0);                                                 \
    STAGE1(Aptr, bm, 0, 1, As, 0);                                                 \
    STAGE1(Bptr, bn, 0, 1, Bs, 0);                                                 \
    STAGE1(Aptr, bm, 1, 0, As, 1);                                                 \
    STAGE1(Bptr, bn, 1, 0, Bs, 1);                                                 \
    VMCNT(8);                                                                      \
    __builtin_amdgcn_s_barrier();                                                  \
    _Pragma("unroll 1")                                                            \
    for (int j = 0; j < NKT; j += 2) {                                             \
        KTILE(j, 0)                                                                \
        KTILE(j + 1, 1)                                                            \
    }

// ---------------------------------------------------- out-projection GEMM
__global__ __launch_bounds__(512, 2) void gemm_bt_kernel(const ushort_t* __restrict__ Aptr,
                                                         const ushort_t* __restrict__ Bptr,
                                                         const float* __restrict__ bias,
                                                         float* __restrict__ C,
                                                         int M, int N, int K) {
    __shared__ __align__(16) ushort_t As[2][2][128 * 64];
    __shared__ __align__(16) ushort_t Bs[2][2][128 * 64];
    const int bm = blockIdx.x * 256, bn = blockIdx.y * 256;
    G256_PRELUDE
    G256_MAIN_LOOP
    for (int i = 0; i < 8; ++i)
        for (int jf = 0; jf < 4; ++jf) {
            int col = bn + wc * 64 + jf * 16 + r;
            float bv = bias[col];
            for (int reg = 0; reg < 4; ++reg) {
                int row = bm + wr * 128 + i * 16 + quad * 4 + reg;
                C[(size_t)row * N + col] = acc[i][jf][reg] + bv;
            }
        }
}

// ------------------------------------- QKV GEMM + fused RMSNorm/rearrange
// 256-col tile = two head groups. by: 0..7 -> Q heads 2by,2by+1 (rmsnorm*
// q_scale*SM); 8,9 -> K (rmsnorm*k_scale); 10,11 -> V transposed to Vt.
// wc>>1 selects the head within the tile; wc&1 selects its 64-col half.
__global__ __launch_bounds__(512, 2) void gemm_qkv_kernel(const ushort_t* __restrict__ Aptr,
                                                          const ushort_t* __restrict__ Bptr,
                                                          const float* __restrict__ bias,
                                                          const float* __restrict__ q_scale,
                                                          const float* __restrict__ k_scale,
                                                          ushort_t* __restrict__ Q,
                                                          ushort_t* __restrict__ Kb,
                                                          ushort_t* __restrict__ Vt) {
    __shared__ __align__(16) ushort_t As[2][2][128 * 64];
    __shared__ __align__(16) ushort_t Bs[2][2][128 * 64];
    const int bm = blockIdx.x * 256, bn = blockIdx.y * 256;
    G256_PRELUDE
    G256_MAIN_LOOP

    const int g = blockIdx.y;
    float bj[4];
    for (int jf = 0; jf < 4; ++jf) bj[jf] = bias[bn + wc * 64 + jf * 16 + r];
    for (int i = 0; i < 8; ++i)
        for (int jf = 0; jf < 4; ++jf)
            for (int reg = 0; reg < 4; ++reg) acc[i][jf][reg] += bj[jf];

    const int n = bm >> 11, lb = bm & 2047;
    const int hh = wc >> 1, dbase = (wc & 1) * 64;
    if (g < 10) {
        // rmsnorm row-sums: partial over this wave's 64 cols, LDS-combine
        // the (wc&1)=0/1 wave pair of the same head. All K-loop LDS reads
        // retired before the loop's final barrier -> As reuse is safe.
        float* ssum = (float*)&As[0][0][0];   // [wr][hh][wc&1][128]
        for (int i = 0; i < 8; ++i)
            for (int reg = 0; reg < 4; ++reg) {
                float p = 0.f;
                for (int jf = 0; jf < 4; ++jf) p += acc[i][jf][reg] * acc[i][jf][reg];
                p += __shfl_xor(p, 1); p += __shfl_xor(p, 2);
                p += __shfl_xor(p, 4); p += __shfl_xor(p, 8);
                if (r == 0)
                    ssum[(((wr * 2 + hh) * 2) + (wc & 1)) * 128 + i * 16 + quad * 4 + reg] = p;
            }
        __syncthreads();
        const float* scp = (g < 8) ? q_scale : k_scale;
        const float smul = (g < 8) ? SM_SCALE : 1.0f;
        float scj[4];
        for (int jf = 0; jf < 4; ++jf) scj[jf] = scp[dbase + jf * 16 + r];
        ushort_t* dst = (g < 8) ? (Q  + (size_t)(n * 16 + g * 2 + hh) * SEQ * HD)
                                : (Kb + (size_t)(n * 4 + (g - 8) * 2 + hh) * SEQ * HD);
        const int sbase = ((wr * 2 + hh) * 2) * 128;
        for (int i = 0; i < 8; ++i)
            for (int reg = 0; reg < 4; ++reg) {
                int rl = i * 16 + quad * 4 + reg;
                float ss = ssum[sbase + rl] + ssum[sbase + 128 + rl];
                float iv = rsqrtf(ss * (1.0f / 128.0f) + 1e-6f) * smul;
                size_t lrow = lb + wr * 128 + rl;
                for (int jf = 0; jf < 4; ++jf)
                    dst[lrow * HD + dbase + jf * 16 + r] = f2bf(acc[i][jf][reg] * iv * scj[jf]);
            }
    } else {
        // V: write transposed directly, packing 4 consecutive l per lane (8 B)
        ushort_t* dstT = Vt + (size_t)(n * 4 + (g - 10) * 2 + hh) * HD * SEQ;
        for (int i = 0; i < 8; ++i)
            for (int jf = 0; jf < 4; ++jf) {
                int d = dbase + jf * 16 + r;
                ushort_t o[4];
                for (int reg = 0; reg < 4; ++reg) o[reg] = f2bf(acc[i][jf][reg]);
                *(uint2*)&dstT[(size_t)d * SEQ + lb + wr * 128 + i * 16 + quad * 4] = *(uint2*)o;
            }
    }
}

// --------------------------------------------------- flash causal attention
// (unchanged this round — GEMM restructure is the single variable)
__global__ __launch_bounds__(256, 2) void attn_kernel(const ushort_t* __restrict__ Q,
                                                      const ushort_t* __restrict__ K,
                                                      const ushort_t* __restrict__ Vt,
                                                      ushort_t* __restrict__ Y) {
    const int pid = blockIdx.x, h = blockIdx.y, n = blockIdx.z;
    const int kvh = h >> 2;
    const ushort_t* Qp = Q  + (size_t)(n * N_HEADS + h) * SEQ * HD;
    const ushort_t* Kp = K  + (size_t)(n * N_KV + kvh) * SEQ * HD;
    const ushort_t* Vp = Vt + (size_t)(n * N_KV + kvh) * HD * SEQ;   // [d][l]

    __shared__ ushort_t Ks[2][64][128];   // 32 KB, chunk-swizzled, dbuf
    __shared__ ushort_t Vts[2][128][64];  // 32 KB, chunk-swizzled ([d][key]), dbuf
    __shared__ ushort_t Ps[128][64];      // 16 KB, row-chunk-xor swizzled

    const int t = threadIdx.x, w = t >> 6, lane = t & 63, quad = lane >> 4, r = lane & 15;

#define ATTN_STAGE(ct, b)                                                           \
    for (int i = 0; i < 4; ++i) {                                                   \
        int ci = (w * 4 + i) * 64 + lane;                                           \
        {   /* K tile 64x128: 16 chunks/row */                                      \
            int row = ci >> 4, c = ci & 15, cg = c ^ (row & 7);                     \
            gload16(&Kp[(size_t)((ct) * 64 + row) * HD + cg * 8],                   \
                    &Ks[b][0][0] + (w * 4 + i) * 512);                              \
        }                                                                           \
        {   /* Vt tile 128x64: 8 chunks/row */                                      \
            int row = ci >> 3, c = ci & 7, cg = c ^ (row & 7);                      \
            gload16(&Vp[(size_t)row * SEQ + (ct) * 64 + cg * 8],                    \
                    &Vts[b][0][0] + (w * 4 + i) * 512);                             \
        }                                                                           \
    }

    for (int rep = 0; rep < 2; ++rep) {
        const int qt = rep ? (15 - pid) : pid;
        const int q0 = qt * 128;

        __syncthreads();   // prev rep's LDS reads done before restaging buf 0
        ATTN_STAGE(0, 0)

        // Q fragments straight from global (A-layout is contiguous 16B/lane)
        bf16x8 aq[2][4];
        for (int s = 0; s < 2; ++s)
            for (int kc = 0; kc < 4; ++kc)
                aq[s][kc] = *(const bf16x8*)&Qp[(size_t)(q0 + w * 32 + s * 16 + r) * HD + kc * 32 + quad * 8];

        f32x4 oacc[2][8] = {};
        float lsum[2][4] = {};
        const int nct = 2 * qt + 2;
        int buf = 0;

        for (int ct = 0; ct < nct; ++ct) {
            __syncthreads();   // drains DMA into buf; all reads of buf^1 done
            if (ct + 1 < nct) { ATTN_STAGE(ct + 1, buf ^ 1) }

            // skip tiles entirely above the causal boundary for this wave
            if (ct * 64 <= q0 + w * 32 + 31) {
                // S strips [2 x 16 x 64]: QK^T (scale folded into Q)
                f32x4 sacc[2][4] = {};
                for (int kc = 0; kc < 4; ++kc)
                    for (int jt = 0; jt < 4; ++jt) {
                        bf16x8 bk = *(const bf16x8*)&Ks[buf][jt * 16 + r][((kc * 4 + quad) ^ (r & 7)) * 8];
                        sacc[0][jt] = __builtin_amdgcn_mfma_f32_16x16x32_bf16(aq[0][kc], bk, sacc[0][jt], 0, 0, 0);
                        sacc[1][jt] = __builtin_amdgcn_mfma_f32_16x16x32_bf16(aq[1][kc], bk, sacc[1][jt], 0, 0, 0);
                    }

                // fixed-max softmax; P truncated bf16; row-chunk-xor swizzle
                const bool diag = (ct >= 2 * qt);
                for (int s = 0; s < 2; ++s)
                    for (int reg = 0; reg < 4; ++reg) {
                        int prow = w * 32 + s * 16 + quad * 4 + reg;
                        int qg = q0 + prow;
                        float rs = 0.f;
                        for (int jt = 0; jt < 4; ++jt) {
                            float sv = sacc[s][jt][reg];
                            if (diag && (ct * 64 + jt * 16 + r) > qg) sv = -1e30f;
                            float p = __expf(sv);
                            rs += p;
                            int colp = ((((jt * 2 + (r >> 3)) ^ prow) & 7) << 3) | (r & 7);
                            Ps[prow][colp] = (ushort_t)(__float_as_uint(p) >> 16);
                        }
                        lsum[s][reg] += rs;
                    }

                // PV: O[2x16x128] += P @ V ; bv shared by strips; Ps wave-private
                for (int kk = 0; kk < 64; kk += 32) {
                    bf16x8 pa[2];
                    for (int s = 0; s < 2; ++s) {
                        int row = w * 32 + s * 16 + r;
                        pa[s] = *(const bf16x8*)&Ps[row][((((kk >> 3) + quad) ^ row) & 7) * 8];
                    }
                    for (int dt = 0; dt < 8; ++dt) {
                        bf16x8 bv = *(const bf16x8*)&Vts[buf][dt * 16 + r][((((kk >> 3) + quad) ^ (r & 7)) & 7) * 8];
                        oacc[0][dt] = __builtin_amdgcn_mfma_f32_16x16x32_bf16(pa[0], bv, oacc[0][dt], 0, 0, 0);
                        oacc[1][dt] = __builtin_amdgcn_mfma_f32_16x16x32_bf16(pa[1], bv, oacc[1][dt], 0, 0, 0);
                    }
                }
            }
            buf ^= 1;
        }

        // epilogue: end-of-loop row-sum reduction, then Y
        for (int s = 0; s < 2; ++s)
            for (int reg = 0; reg < 4; ++reg) {
                float sv = lsum[s][reg];
                for (int m = 1; m < 16; m <<= 1) sv += __shfl_xor(sv, m);
                float invl = 1.0f / sv;
                int lrow = q0 + w * 32 + s * 16 + quad * 4 + reg;
                size_t base = ((size_t)(n * SEQ + lrow)) * D_MODEL + h * HD;
                for (int dt = 0; dt < 8; ++dt)
                    Y[base + dt * 16 + r] = f2bf(oacc[s][dt][reg] * invl);
            }
    }
#undef ATTN_STAGE
}

// ------------------------------------------------------------------ launch
extern "C" void kernel_launch(void* const* d_in, const int* in_sizes, int n_in,
                              void* d_out, int out_size, void* d_ws, size_t ws_size,
                              hipStream_t stream) {
    const float* x       = (const float*)d_in[0];
    const float* Wqkv    = (const float*)d_in[1];
    const float* bqkv    = (const float*)d_in[2];
    const float* q_scale = (const float*)d_in[3];
    const float* k_scale = (const float*)d_in[4];
    const float* Wout    = (const float*)d_in[5];
    const float* bout    = (const float*)d_in[6];
    float* out = (float*)d_out;

    ushort_t* xb  = (ushort_t*)d_ws;                        // 8192*2048 (later: y)
    ushort_t* WT  = xb  + (size_t)MROWS * D_MODEL;          // 3072*2048 (later: WoutT)
    ushort_t* Qb  = WT  + (size_t)NQKV * D_MODEL;           // 4*16*2048*128
    ushort_t* Kb  = Qb  + (size_t)NB * N_HEADS * SEQ * HD;  // 4*4*2048*128
    ushort_t* Vtb = Kb  + (size_t)NB * N_KV * SEQ * HD;     // 4*4*128*2048

    conv_x_kernel<<<MROWS * D_MODEL / 1024, 256, 0, stream>>>(x, xb, MROWS * D_MODEL);
    conv_wt_kernel<<<dim3(NQKV / 32, D_MODEL / 32), dim3(32, 8), 0, stream>>>(Wqkv, WT, D_MODEL, NQKV);
    gemm_qkv_kernel<<<dim3(MROWS / 256, NQKV / 256), 512, 0, stream>>>(xb, WT, bqkv, q_scale, k_scale, Qb, Kb, Vtb);
    conv_wt_kernel<<<dim3(D_MODEL / 32, D_MODEL / 32), dim3(32, 8), 0, stream>>>(Wout, WT, D_MODEL, D_MODEL);
    attn_kernel<<<dim3(8, N_HEADS, NB), 256, 0, stream>>>(Qb, Kb, Vtb, xb);
    gemm_bt_kernel<<<dim3(MROWS / 256, D_MODEL / 256), 512, 0, stream>>>(xb, WT, bout, out, MROWS, D_MODEL, D_MODEL);
}

// Round 3
// 455.483 us; speedup vs baseline: 1.0357x; 1.0357x over previous
//
#include <hip/hip_runtime.h>

typedef unsigned int uint_t;
typedef unsigned short ushort_t;

using f32x4 = __attribute__((ext_vector_type(4))) float;
using bf16x8 = __attribute__((ext_vector_type(8))) short;

#define D_MODEL 2048
#define N_HEADS 16
#define N_KV    4
#define HD      128
#define KV_DIM  (N_KV * HD)          // 512
#define NQKV    (D_MODEL + 2*KV_DIM) // 3072
#define SEQ     2048
#define NB      4
#define MROWS   (NB * SEQ)           // 8192
#define NKT     32                   // K/64, K=2048 for both GEMMs
#define SM_SCALE 0.08838834764831845f  // 1/sqrt(128)

__device__ __forceinline__ ushort_t f2bf(float f) {
    uint_t u = __float_as_uint(f);
    u = (u + 0x7FFFu + ((u >> 16) & 1u)) >> 16;   // RNE
    return (ushort_t)u;
}

// async global->LDS, 16 B/lane, lands at (wave-uniform lds base) + lane*16
__device__ __forceinline__ void gload16(const ushort_t* g, ushort_t* l) {
    __builtin_amdgcn_global_load_lds(
        (const __attribute__((address_space(1))) unsigned int*)g,
        (__attribute__((address_space(3))) unsigned int*)l, 16, 0, 0);
}

// NO "memory" clobber (the R1->R3 single variable). The clobber was a full
// compiler fence at every window seam -> pinned ds_reads behind it -> LDS
// service serialized with MFMA windows (R1: 30% MfmaUtil, 725 TF = drain-0
// level). Bare volatile asm keeps ordering vs gload_lds/barriers (both
// volatile) but lets the scheduler hoist next-window ds_read_b128s into
// the MFMA window tail (m201 template uses bare asm waits for this reason).
#define VMCNT(N) asm volatile("s_waitcnt vmcnt(" #N ")")

// ---------------------------------------------------------------- conv_x
__global__ __launch_bounds__(256) void conv_x_kernel(const float* __restrict__ in,
                                                     ushort_t* __restrict__ out, int n) {
    int i = (blockIdx.x * 256 + threadIdx.x) * 4;
    if (i >= n) return;
    float4 v = *(const float4*)&in[i];
    ushort_t o[4] = {f2bf(v.x), f2bf(v.y), f2bf(v.z), f2bf(v.w)};
    *(uint2*)&out[i] = *(uint2*)o;
}

// ------------------------------------------------------ transpose + cast
// W [K][Nout] fp32 -> WT [Nout][K] bf16
__global__ __launch_bounds__(256) void conv_wt_kernel(const float* __restrict__ W,
                                                      ushort_t* __restrict__ WT,
                                                      int K, int Nout) {
    __shared__ float tile[32][33];
    int n0 = blockIdx.x * 32, k0 = blockIdx.y * 32;
    int tx = threadIdx.x, ty = threadIdx.y;  // (32, 8)
    for (int i = 0; i < 4; ++i)
        tile[ty + 8*i][tx] = W[(size_t)(k0 + ty + 8*i) * Nout + n0 + tx];
    __syncthreads();
    for (int i = 0; i < 4; ++i)
        WT[(size_t)(n0 + ty + 8*i) * K + k0 + tx] = f2bf(tile[tx][ty + 8*i]);
}

// ======================================================================
// 256x256 8-phase GEMM core (T2+T3+T4+T5). 512 thr = 8 waves (2M x 4N),
// wave tile 128x64. BK=64 as two K-halves of 32. LDS = 2buf x 2kh x
// (256rows x 32k) x {A,B} = 128 KiB. Per K-tile: 4 phases, each
// {ds_read subtile; stage 1 half (2 gload16); barrier; setprio(1);
//  16 MFMA; setprio(0); [vmcnt]; barrier}. vmcnt(8) at odd phases only
// (never 0 mid-loop): every drained half was issued 3+ phases earlier.
// Slot safety: kh0 slot of buf is free after phase1 (staged at phase2
// for K-tile j+2); kh1 slot of buf^1 free after prev tile's phase3
// (staged at phase0 for j+1). LDS layout packs 2 M-rows per 128-B LDS
// row; chunk = ((row&1)<<2 | kchunk) ^ (lrow&7): each aligned 8-lane
// group of ds_read_b128 hits 8 distinct 16B chunks -> conflict-free
// (SQ_LDS_BANK_CONFLICT = 0 measured in R1).
// ======================================================================
#define G256_PRELUDE                                                               \
    const int t = threadIdx.x;                                                     \
    const int wid = t >> 6, lane = t & 63, quad = lane >> 4, r = lane & 15;        \
    const int wr = wid >> 2, wc = wid & 3;                                         \
    int srow[2], skc[2], sdst[2];                                                  \
    for (int l = 0; l < 2; ++l) {                                                  \
        int u = l * 512 + t, lrow = u >> 3, cc = (u & 7) ^ (lrow & 7);             \
        srow[l] = lrow * 2 + (cc >> 2); skc[l] = (cc & 3) * 8; sdst[l] = u * 8;    \
    }                                                                              \
    const int swz  = ((((r & 1) << 2) | quad) ^ ((r >> 1) & 7)) * 8;               \
    const int aoff = (wr * 64 + (r >> 1)) * 64 + swz;                              \
    const int boff = (wc * 32 + (r >> 1)) * 64 + swz;                              \
    f32x4 acc[8][4] = {};                                                          \
    bf16x8 bfr[4];

// stage one K-half (256 rows x 32 k) of an operand; global source is
// pre-inverse-swizzled so LDS stays linear for the DMA (rule 21).
#define STAGE1(PTR, ROWBASE, kt, kh, DST, dbuf)                                    \
    if ((kt) < NKT) {                                                              \
        for (int l = 0; l < 2; ++l)                                                \
            gload16(&PTR[(size_t)((ROWBASE) + srow[l]) * 2048 +                    \
                         (kt) * 64 + (kh) * 32 + skc[l]],                          \
                    &DST[dbuf][kh][0] + sdst[l]);                                  \
    }

#define PHASE(buf, kh, mh, STAGE_STMT, VM_STMT)                                    \
    {                                                                              \
        bf16x8 af[4];                                                              \
        for (int i = 0; i < 4; ++i)                                                \
            af[i] = *(const bf16x8*)&As[buf][kh][aoff + ((mh) * 4 + i) * 512];     \
        if ((mh) == 0)                                                             \
            for (int jf = 0; jf < 4; ++jf)                                         \
                bfr[jf] = *(const bf16x8*)&Bs[buf][kh][boff + jf * 512];           \
        STAGE_STMT;                                                                \
        __builtin_amdgcn_s_barrier();                                              \
        __builtin_amdgcn_s_setprio(1);                                             \
        for (int i = 0; i < 4; ++i)                                                \
            for (int jf = 0; jf < 4; ++jf)                                         \
                acc[(mh) * 4 + i][jf] = __builtin_amdgcn_mfma_f32_16x16x32_bf16(   \
                    af[i], bfr[jf], acc[(mh) * 4 + i][jf], 0, 0, 0);               \
        __builtin_amdgcn_s_setprio(0);                                             \
        VM_STMT;                                                                   \
        __builtin_amdgcn_s_barrier();                                              \
    }

#define KTILE(j, buf)                                                              \
    PHASE(buf, 0, 0, STAGE1(Aptr, bm, (j) + 1, 1, As, (buf) ^ 1), ;)               \
    PHASE(buf, 0, 1, STAGE1(Bptr, bn, (j) + 1, 1, Bs, (buf) ^ 1),                  \
          { if ((j) + 1 < NKT) { VMCNT(8); } else { VMCNT(0); } })                 \
    PHASE(buf, 1, 0, STAGE1(Aptr, bm, (j) + 2, 0, As, buf), ;)                     \
    PHASE(buf, 1, 1, STAGE1(Bptr, bn, (j) + 2, 0, Bs, buf),                        \
          { if ((j) + 2 < NKT) { VMCNT(8); }                                       \
            else if ((j) + 1 < NKT) { VMCNT(4); }                                  \
            else { VMCNT(0); } })

// prologue: A0(0) B0(0) A1(0) B1(0) A0(1) B0(1); vmcnt(8) drains K-tile0's
// kh0 halves (oldest 4 loads); kh1 halves drain at phase1's vmcnt(8).
#define G256_MAIN_LOOP                                                             \
    STAGE1(Aptr, bm, 0, 0, As, 0);                                                 \
    STAGE1(Bptr, bn, 0, 0, Bs, 0);                                                 \
    STAGE1(Aptr, bm, 0, 1, As, 0);                                                 \
    STAGE1(Bptr, bn, 0, 1, Bs, 0);                                                 \
    STAGE1(Aptr, bm, 1, 0, As, 1);                                                 \
    STAGE1(Bptr, bn, 1, 0, Bs, 1);                                                 \
    VMCNT(8);                                                                      \
    __builtin_amdgcn_s_barrier();                                                  \
    _Pragma("unroll 1")                                                            \
    for (int j = 0; j < NKT; j += 2) {                                             \
        KTILE(j, 0)                                                                \
        KTILE(j + 1, 1)                                                            \
    }

// ---------------------------------------------------- out-projection GEMM
__global__ __launch_bounds__(512, 2) void gemm_bt_kernel(const ushort_t* __restrict__ Aptr,
                                                         const ushort_t* __restrict__ Bptr,
                                                         const float* __restrict__ bias,
                                                         float* __restrict__ C,
                                                         int M, int N, int K) {
    __shared__ __align__(16) ushort_t As[2][2][128 * 64];
    __shared__ __align__(16) ushort_t Bs[2][2][128 * 64];
    const int bm = blockIdx.x * 256, bn = blockIdx.y * 256;
    G256_PRELUDE
    G256_MAIN_LOOP
    for (int i = 0; i < 8; ++i)
        for (int jf = 0; jf < 4; ++jf) {
            int col = bn + wc * 64 + jf * 16 + r;
            float bv = bias[col];
            for (int reg = 0; reg < 4; ++reg) {
                int row = bm + wr * 128 + i * 16 + quad * 4 + reg;
                C[(size_t)row * N + col] = acc[i][jf][reg] + bv;
            }
        }
}

// ------------------------------------- QKV GEMM + fused RMSNorm/rearrange
// 256-col tile = two head groups. by: 0..7 -> Q heads 2by,2by+1 (rmsnorm*
// q_scale*SM); 8,9 -> K (rmsnorm*k_scale); 10,11 -> V transposed to Vt.
// wc>>1 selects the head within the tile; wc&1 selects its 64-col half.
__global__ __launch_bounds__(512, 2) void gemm_qkv_kernel(const ushort_t* __restrict__ Aptr,
                                                          const ushort_t* __restrict__ Bptr,
                                                          const float* __restrict__ bias,
                                                          const float* __restrict__ q_scale,
                                                          const float* __restrict__ k_scale,
                                                          ushort_t* __restrict__ Q,
                                                          ushort_t* __restrict__ Kb,
                                                          ushort_t* __restrict__ Vt) {
    __shared__ __align__(16) ushort_t As[2][2][128 * 64];
    __shared__ __align__(16) ushort_t Bs[2][2][128 * 64];
    const int bm = blockIdx.x * 256, bn = blockIdx.y * 256;
    G256_PRELUDE
    G256_MAIN_LOOP

    const int g = blockIdx.y;
    float bj[4];
    for (int jf = 0; jf < 4; ++jf) bj[jf] = bias[bn + wc * 64 + jf * 16 + r];
    for (int i = 0; i < 8; ++i)
        for (int jf = 0; jf < 4; ++jf)
            for (int reg = 0; reg < 4; ++reg) acc[i][jf][reg] += bj[jf];

    const int n = bm >> 11, lb = bm & 2047;
    const int hh = wc >> 1, dbase = (wc & 1) * 64;
    if (g < 10) {
        // rmsnorm row-sums: partial over this wave's 64 cols, LDS-combine
        // the (wc&1)=0/1 wave pair of the same head. All K-loop LDS reads
        // retired before the loop's final barrier -> As reuse is safe.
        float* ssum = (float*)&As[0][0][0];   // [wr][hh][wc&1][128]
        for (int i = 0; i < 8; ++i)
            for (int reg = 0; reg < 4; ++reg) {
                float p = 0.f;
                for (int jf = 0; jf < 4; ++jf) p += acc[i][jf][reg] * acc[i][jf][reg];
                p += __shfl_xor(p, 1); p += __shfl_xor(p, 2);
                p += __shfl_xor(p, 4); p += __shfl_xor(p, 8);
                if (r == 0)
                    ssum[(((wr * 2 + hh) * 2) + (wc & 1)) * 128 + i * 16 + quad * 4 + reg] = p;
            }
        __syncthreads();
        const float* scp = (g < 8) ? q_scale : k_scale;
        const float smul = (g < 8) ? SM_SCALE : 1.0f;
        float scj[4];
        for (int jf = 0; jf < 4; ++jf) scj[jf] = scp[dbase + jf * 16 + r];
        ushort_t* dst = (g < 8) ? (Q  + (size_t)(n * 16 + g * 2 + hh) * SEQ * HD)
                                : (Kb + (size_t)(n * 4 + (g - 8) * 2 + hh) * SEQ * HD);
        const int sbase = ((wr * 2 + hh) * 2) * 128;
        for (int i = 0; i < 8; ++i)
            for (int reg = 0; reg < 4; ++reg) {
                int rl = i * 16 + quad * 4 + reg;
                float ss = ssum[sbase + rl] + ssum[sbase + 128 + rl];
                float iv = rsqrtf(ss * (1.0f / 128.0f) + 1e-6f) * smul;
                size_t lrow = lb + wr * 128 + rl;
                for (int jf = 0; jf < 4; ++jf)
                    dst[lrow * HD + dbase + jf * 16 + r] = f2bf(acc[i][jf][reg] * iv * scj[jf]);
            }
    } else {
        // V: write transposed directly, packing 4 consecutive l per lane (8 B)
        ushort_t* dstT = Vt + (size_t)(n * 4 + (g - 10) * 2 + hh) * HD * SEQ;
        for (int i = 0; i < 8; ++i)
            for (int jf = 0; jf < 4; ++jf) {
                int d = dbase + jf * 16 + r;
                ushort_t o[4];
                for (int reg = 0; reg < 4; ++reg) o[reg] = f2bf(acc[i][jf][reg]);
                *(uint2*)&dstT[(size_t)d * SEQ + lb + wr * 128 + i * 16 + quad * 4] = *(uint2*)o;
            }
    }
}

// --------------------------------------------------- flash causal attention
// (unchanged — GEMM clobber fix is the single variable this round)
__global__ __launch_bounds__(256, 2) void attn_kernel(const ushort_t* __restrict__ Q,
                                                      const ushort_t* __restrict__ K,
                                                      const ushort_t* __restrict__ Vt,
                                                      ushort_t* __restrict__ Y) {
    const int pid = blockIdx.x, h = blockIdx.y, n = blockIdx.z;
    const int kvh = h >> 2;
    const ushort_t* Qp = Q  + (size_t)(n * N_HEADS + h) * SEQ * HD;
    const ushort_t* Kp = K  + (size_t)(n * N_KV + kvh) * SEQ * HD;
    const ushort_t* Vp = Vt + (size_t)(n * N_KV + kvh) * HD * SEQ;   // [d][l]

    __shared__ ushort_t Ks[2][64][128];   // 32 KB, chunk-swizzled, dbuf
    __shared__ ushort_t Vts[2][128][64];  // 32 KB, chunk-swizzled ([d][key]), dbuf
    __shared__ ushort_t Ps[128][64];      // 16 KB, row-chunk-xor swizzled

    const int t = threadIdx.x, w = t >> 6, lane = t & 63, quad = lane >> 4, r = lane & 15;

#define ATTN_STAGE(ct, b)                                                           \
    for (int i = 0; i < 4; ++i) {                                                   \
        int ci = (w * 4 + i) * 64 + lane;                                           \
        {   /* K tile 64x128: 16 chunks/row */                                      \
            int row = ci >> 4, c = ci & 15, cg = c ^ (row & 7);                     \
            gload16(&Kp[(size_t)((ct) * 64 + row) * HD + cg * 8],                   \
                    &Ks[b][0][0] + (w * 4 + i) * 512);                              \
        }                                                                           \
        {   /* Vt tile 128x64: 8 chunks/row */                                      \
            int row = ci >> 3, c = ci & 7, cg = c ^ (row & 7);                      \
            gload16(&Vp[(size_t)row * SEQ + (ct) * 64 + cg * 8],                    \
                    &Vts[b][0][0] + (w * 4 + i) * 512);                             \
        }                                                                           \
    }

    for (int rep = 0; rep < 2; ++rep) {
        const int qt = rep ? (15 - pid) : pid;
        const int q0 = qt * 128;

        __syncthreads();   // prev rep's LDS reads done before restaging buf 0
        ATTN_STAGE(0, 0)

        // Q fragments straight from global (A-layout is contiguous 16B/lane)
        bf16x8 aq[2][4];
        for (int s = 0; s < 2; ++s)
            for (int kc = 0; kc < 4; ++kc)
                aq[s][kc] = *(const bf16x8*)&Qp[(size_t)(q0 + w * 32 + s * 16 + r) * HD + kc * 32 + quad * 8];

        f32x4 oacc[2][8] = {};
        float lsum[2][4] = {};
        const int nct = 2 * qt + 2;
        int buf = 0;

        for (int ct = 0; ct < nct; ++ct) {
            __syncthreads();   // drains DMA into buf; all reads of buf^1 done
            if (ct + 1 < nct) { ATTN_STAGE(ct + 1, buf ^ 1) }

            // skip tiles entirely above the causal boundary for this wave
            if (ct * 64 <= q0 + w * 32 + 31) {
                // S strips [2 x 16 x 64]: QK^T (scale folded into Q)
                f32x4 sacc[2][4] = {};
                for (int kc = 0; kc < 4; ++kc)
                    for (int jt = 0; jt < 4; ++jt) {
                        bf16x8 bk = *(const bf16x8*)&Ks[buf][jt * 16 + r][((kc * 4 + quad) ^ (r & 7)) * 8];
                        sacc[0][jt] = __builtin_amdgcn_mfma_f32_16x16x32_bf16(aq[0][kc], bk, sacc[0][jt], 0, 0, 0);
                        sacc[1][jt] = __builtin_amdgcn_mfma_f32_16x16x32_bf16(aq[1][kc], bk, sacc[1][jt], 0, 0, 0);
                    }

                // fixed-max softmax; P truncated bf16; row-chunk-xor swizzle
                const bool diag = (ct >= 2 * qt);
                for (int s = 0; s < 2; ++s)
                    for (int reg = 0; reg < 4; ++reg) {
                        int prow = w * 32 + s * 16 + quad * 4 + reg;
                        int qg = q0 + prow;
                        float rs = 0.f;
                        for (int jt = 0; jt < 4; ++jt) {
                            float sv = sacc[s][jt][reg];
                            if (diag && (ct * 64 + jt * 16 + r) > qg) sv = -1e30f;
                            float p = __expf(sv);
                            rs += p;
                            int colp = ((((jt * 2 + (r >> 3)) ^ prow) & 7) << 3) | (r & 7);
                            Ps[prow][colp] = (ushort_t)(__float_as_uint(p) >> 16);
                        }
                        lsum[s][reg] += rs;
                    }

                // PV: O[2x16x128] += P @ V ; bv shared by strips; Ps wave-private
                for (int kk = 0; kk < 64; kk += 32) {
                    bf16x8 pa[2];
                    for (int s = 0; s < 2; ++s) {
                        int row = w * 32 + s * 16 + r;
                        pa[s] = *(const bf16x8*)&Ps[row][((((kk >> 3) + quad) ^ row) & 7) * 8];
                    }
                    for (int dt = 0; dt < 8; ++dt) {
                        bf16x8 bv = *(const bf16x8*)&Vts[buf][dt * 16 + r][((((kk >> 3) + quad) ^ (r & 7)) & 7) * 8];
                        oacc[0][dt] = __builtin_amdgcn_mfma_f32_16x16x32_bf16(pa[0], bv, oacc[0][dt], 0, 0, 0);
                        oacc[1][dt] = __builtin_amdgcn_mfma_f32_16x16x32_bf16(pa[1], bv, oacc[1][dt], 0, 0, 0);
                    }
                }
            }
            buf ^= 1;
        }

        // epilogue: end-of-loop row-sum reduction, then Y
        for (int s = 0; s < 2; ++s)
            for (int reg = 0; reg < 4; ++reg) {
                float sv = lsum[s][reg];
                for (int m = 1; m < 16; m <<= 1) sv += __shfl_xor(sv, m);
                float invl = 1.0f / sv;
                int lrow = q0 + w * 32 + s * 16 + quad * 4 + reg;
                size_t base = ((size_t)(n * SEQ + lrow)) * D_MODEL + h * HD;
                for (int dt = 0; dt < 8; ++dt)
                    Y[base + dt * 16 + r] = f2bf(oacc[s][dt][reg] * invl);
            }
    }
#undef ATTN_STAGE
}

// ------------------------------------------------------------------ launch
extern "C" void kernel_launch(void* const* d_in, const int* in_sizes, int n_in,
                              void* d_out, int out_size, void* d_ws, size_t ws_size,
                              hipStream_t stream) {
    const float* x       = (const float*)d_in[0];
    const float* Wqkv    = (const float*)d_in[1];
    const float* bqkv    = (const float*)d_in[2];
    const float* q_scale = (const float*)d_in[3];
    const float* k_scale = (const float*)d_in[4];
    const float* Wout    = (const float*)d_in[5];
    const float* bout    = (const float*)d_in[6];
    float* out = (float*)d_out;

    ushort_t* xb  = (ushort_t*)d_ws;                        // 8192*2048 (later: y)
    ushort_t* WT  = xb  + (size_t)MROWS * D_MODEL;          // 3072*2048 (later: WoutT)
    ushort_t* Qb  = WT  + (size_t)NQKV * D_MODEL;           // 4*16*2048*128
    ushort_t* Kb  = Qb  + (size_t)NB * N_HEADS * SEQ * HD;  // 4*4*2048*128
    ushort_t* Vtb = Kb  + (size_t)NB * N_KV * SEQ * HD;     // 4*4*128*2048

    conv_x_kernel<<<MROWS * D_MODEL / 1024, 256, 0, stream>>>(x, xb, MROWS * D_MODEL);
    conv_wt_kernel<<<dim3(NQKV / 32, D_MODEL / 32), dim3(32, 8), 0, stream>>>(Wqkv, WT, D_MODEL, NQKV);
    gemm_qkv_kernel<<<dim3(MROWS / 256, NQKV / 256), 512, 0, stream>>>(xb, WT, bqkv, q_scale, k_scale, Qb, Kb, Vtb);
    conv_wt_kernel<<<dim3(D_MODEL / 32, D_MODEL / 32), dim3(32, 8), 0, stream>>>(Wout, WT, D_MODEL, D_MODEL);
    attn_kernel<<<dim3(8, N_HEADS, NB), 256, 0, stream>>>(Qb, Kb, Vtb, xb);
    gemm_bt_kernel<<<dim3(MROWS / 256, D_MODEL / 256), 512, 0, stream>>>(xb, WT, bout, out, MROWS, D_MODEL, D_MODEL);
}